// Round 9
// baseline (292.618 us; speedup 1.0000x reference)
//
#include <hip/hip_runtime.h>
#include <hip/hip_bf16.h>

#define NN 100000
#define EE 1200000
#define F1 128
#define F2 256
#define F3 40
#define MROWS 64
#define NBUK ((NN + 255) / 256)          // 391 coarse buckets (256 nodes each)
#define NBLK 1024                        // scatter blocks (4/CU: latency hiding)
#define CHUNK ((EE + NBLK - 1) / NBLK)   // 1172 edges per block
#define DCAP 4096                        // fixed slots per bucket (mean 3070, +18 sigma)
#define BSTR 16                          // bcur stride: 1 counter per 64B sector
#define XB2 ((NN * 32 + 255) / 256)      // 12500 blocks for x-prep (float4 granularity)
#define WB ((F1 * F2 + F2 * 48 + 255) / 256)   // 176 weight-pack blocks

typedef __bf16 bf16x8 __attribute__((ext_vector_type(8)));
typedef float  f32x4  __attribute__((ext_vector_type(4)));

__device__ __forceinline__ unsigned short f2bf(float f) {   // RNE bf16
    unsigned u = __float_as_uint(f);
    return (unsigned short)((u + 0x7fffu + ((u >> 16) & 1u)) >> 16);
}
__device__ __forceinline__ float bflo(unsigned v) { return __uint_as_float(v << 16); }
__device__ __forceinline__ float bfhi(unsigned v) { return __uint_as_float(v & 0xffff0000u); }

// ---- pass 1 (single-pass hist+reserve+scatter), 1024 blocks for occupancy.
// Caches chunk records in LDS, one padded global atomicAdd per (block,bucket),
// scatters from LDS into the bucket's fixed region rec[bucket*DCAP...]. ----
__global__ __launch_bounds__(256) void k_scatA(const int* __restrict__ row,
                                               const int* __restrict__ col,
                                               int* __restrict__ bcur,
                                               unsigned* __restrict__ rec) {
    __shared__ int lh[NBUK];                 // local count, then local cursor
    __shared__ int lbase[NBUK];              // reserved global base per bucket
    __shared__ unsigned lrec[CHUNK];         // 4.7 KB cached records
    __shared__ unsigned short lbuk[CHUNK];   // 2.3 KB bucket ids (0xFFFF = skip)
    for (int i = threadIdx.x; i < NBUK; i += 256) lh[i] = 0;
    __syncthreads();
    const int e0 = blockIdx.x * CHUNK;
    const int ne = min(CHUNK, EE - e0);
    for (int j = threadIdx.x; j < ne; j += 256) {
        int e = e0 + j;
        int r = row[e], c = col[e];
        if ((unsigned)c < (unsigned)NN) {
            int b = c >> 8;
            lbuk[j] = (unsigned short)b;
            lrec[j] = ((unsigned)r & 0xFFFFFFu) | ((unsigned)(c & 255) << 24);
            atomicAdd(&lh[b], 1);
        } else {
            lbuk[j] = 0xFFFFu;
        }
    }
    __syncthreads();
    for (int i = threadIdx.x; i < NBUK; i += 256) {
        int cn = lh[i];
        lbase[i] = cn ? atomicAdd(&bcur[i * BSTR], cn) : 0;   // padded counter
        lh[i] = 0;                                            // reuse as cursor
    }
    __syncthreads();
    for (int j = threadIdx.x; j < ne; j += 256) {
        int b = lbuk[j];
        if (b != 0xFFFF) {
            int pos = lbase[b] + atomicAdd(&lh[b], 1); // LDS atomic
            if (pos < DCAP) rec[(size_t)b * DCAP + pos] = lrec[j];
        }
    }
}

// ---- pass 2: bucket -> CSR (LDS-cached sort); cnt/cursor(end)/dinv ----
__global__ __launch_bounds__(256) void k_csr(const int* __restrict__ bcur,
                                             const unsigned* __restrict__ rec,
                                             int* __restrict__ eidx,
                                             int* __restrict__ cnt,
                                             int* __restrict__ cursor,
                                             float* __restrict__ dinv) {
    __shared__ int lcnt[256];
    __shared__ int s[256];
    __shared__ int lcur[256];
    __shared__ unsigned lrec[DCAP];   // 16 KB cached records
    __shared__ int lde[DCAP];         // 16 KB sorted rows
    const int b = blockIdx.x;
    const int tid = threadIdx.x;
    lcnt[tid] = 0;
    __syncthreads();
    const int base = b * DCAP;
    const int nb = min(bcur[b * BSTR], DCAP);
    for (int j = tid; j < nb; j += 256) {
        unsigned v = rec[(size_t)base + j];
        lrec[j] = v;
        atomicAdd(&lcnt[v >> 24], 1);
    }
    __syncthreads();
    int cv = lcnt[tid];
    s[tid] = cv;
    __syncthreads();
    int acc = cv;
    for (int d = 1; d < 256; d <<= 1) {
        int add = (tid >= d) ? s[tid - d] : 0;
        __syncthreads();
        acc += add;
        s[tid] = acc;
        __syncthreads();
    }
    int excl = acc - cv;
    lcur[tid] = excl;
    const int node = (b << 8) + tid;
    if (node < NN) {
        cnt[node] = cv;
        cursor[node] = base + excl + cv;            // END cursor (start = end - cnt)
        dinv[node] = rsqrtf((float)(cv + 1));       // +1 self-loop
    }
    __syncthreads();
    for (int j = tid; j < nb; j += 256) {
        unsigned v = lrec[j];
        int pos = atomicAdd(&lcur[v >> 24], 1);     // LDS atomic
        lde[pos] = (int)(v & 0xFFFFFFu);
    }
    __syncthreads();
    for (int j = tid; j < nb; j += 256) eidx[base + j] = lde[j];
}

// ---- fused prep (standalone, high occupancy): xh = bf16(x*dinv); pack W1,W2 ----
__global__ void k_prep(const float4* __restrict__ x, const float* __restrict__ dinv,
                       uint2* __restrict__ xh,
                       const float* __restrict__ W1, const float* __restrict__ W2,
                       __hip_bfloat16* __restrict__ W1p, __hip_bfloat16* __restrict__ W2p) {
    if (blockIdx.x < XB2) {
        int idx = blockIdx.x * 256 + threadIdx.x;   // NN*32 float4s, exact multiple
        float d = dinv[idx >> 5];
        float4 v = x[idx];
        uint2 o;
        o.x = (unsigned)f2bf(v.x * d) | ((unsigned)f2bf(v.y * d) << 16);
        o.y = (unsigned)f2bf(v.z * d) | ((unsigned)f2bf(v.w * d) << 16);
        xh[idx] = o;
    } else {
        int idx = (blockIdx.x - XB2) * 256 + threadIdx.x;
        if (idx < F1 * F2) {
            int k = idx / F2, col = idx - (idx / F2) * F2;
            int k8 = k >> 3, j = k & 7;
            W1p[((size_t)(k8 * F2 + col) << 3) + j] = __float2bfloat16(W1[(size_t)k * F2 + col]);
        } else if (idx < F1 * F2 + F2 * 48) {
            int i2 = idx - F1 * F2;
            int k = i2 / 48, col = i2 - (i2 / 48) * 48;
            int k8 = k >> 3, j = k & 7;
            float v = (col < F3) ? W2[(size_t)k * F3 + col] : 0.0f;
            W2p[((size_t)(k8 * 48 + col) << 3) + j] = __float2bfloat16(v);
        }
    }
}

// ---- layer-1 pull aggregation: known-good structure (3.65 TB/s, 71% occ) ----
__global__ __launch_bounds__(256) void k_agg1(const int* __restrict__ cursor,
                                              const int* __restrict__ cnt,
                                              const int* __restrict__ eidx,
                                              const float* __restrict__ dinv,
                                              const unsigned* __restrict__ xh,
                                              unsigned* __restrict__ agg) {
    int node = blockIdx.x * 4 + (threadIdx.x >> 6);
    int lane = threadIdx.x & 63;
    if (node >= NN) return;
    unsigned vs = xh[((size_t)node << 6) + lane];
    float a0 = bflo(vs), a1 = bfhi(vs);
    int n = cnt[node];
    int s = cursor[node] - n;
    int k = 0;
    for (; k + 7 < n; k += 8) {
        int r0 = eidx[s + k + 0], r1 = eidx[s + k + 1];
        int r2 = eidx[s + k + 2], r3 = eidx[s + k + 3];
        int r4 = eidx[s + k + 4], r5 = eidx[s + k + 5];
        int r6 = eidx[s + k + 6], r7 = eidx[s + k + 7];
        unsigned v0 = xh[((size_t)r0 << 6) + lane];
        unsigned v1 = xh[((size_t)r1 << 6) + lane];
        unsigned v2 = xh[((size_t)r2 << 6) + lane];
        unsigned v3 = xh[((size_t)r3 << 6) + lane];
        unsigned v4 = xh[((size_t)r4 << 6) + lane];
        unsigned v5 = xh[((size_t)r5 << 6) + lane];
        unsigned v6 = xh[((size_t)r6 << 6) + lane];
        unsigned v7 = xh[((size_t)r7 << 6) + lane];
        a0 += bflo(v0); a1 += bfhi(v0);
        a0 += bflo(v1); a1 += bfhi(v1);
        a0 += bflo(v2); a1 += bfhi(v2);
        a0 += bflo(v3); a1 += bfhi(v3);
        a0 += bflo(v4); a1 += bfhi(v4);
        a0 += bflo(v5); a1 += bfhi(v5);
        a0 += bflo(v6); a1 += bfhi(v6);
        a0 += bflo(v7); a1 += bfhi(v7);
    }
    for (; k + 3 < n; k += 4) {
        int r0 = eidx[s + k + 0], r1 = eidx[s + k + 1];
        int r2 = eidx[s + k + 2], r3 = eidx[s + k + 3];
        unsigned v0 = xh[((size_t)r0 << 6) + lane];
        unsigned v1 = xh[((size_t)r1 << 6) + lane];
        unsigned v2 = xh[((size_t)r2 << 6) + lane];
        unsigned v3 = xh[((size_t)r3 << 6) + lane];
        a0 += bflo(v0); a1 += bfhi(v0);
        a0 += bflo(v1); a1 += bfhi(v1);
        a0 += bflo(v2); a1 += bfhi(v2);
        a0 += bflo(v3); a1 += bfhi(v3);
    }
    for (; k < n; ++k) {
        unsigned v0 = xh[((size_t)eidx[s + k] << 6) + lane];
        a0 += bflo(v0); a1 += bfhi(v0);
    }
    float d = dinv[node];
    agg[((size_t)node << 6) + lane] = (unsigned)f2bf(a0 * d) | ((unsigned)f2bf(a1 * d) << 16);
}

// ---- fused MFMA GEMM1 + ReLU + GEMM2; tg rows PACKED to 40 bf16 (80B, 16B-aligned) ----
__global__ __launch_bounds__(256) void k_gemm_mfma(
    const __hip_bfloat16* __restrict__ agg, const __hip_bfloat16* __restrict__ W1p,
    const float* __restrict__ b1, const __hip_bfloat16* __restrict__ W2p,
    const float* __restrict__ dinv, unsigned short* __restrict__ tg) {
    __shared__ __hip_bfloat16 h_s[MROWS][F2 + 8];   // 33 KB
    const int i0   = blockIdx.x * MROWS;
    const int wave = threadIdx.x >> 6;
    const int lane = threadIdx.x & 63;
    const int m = lane & 15, q = lane >> 4;
    const int rowA = i0 + wave * 16 + m;

    f32x4 acc[16];
#pragma unroll
    for (int c = 0; c < 16; ++c) acc[c] = (f32x4){0.f, 0.f, 0.f, 0.f};

#pragma unroll
    for (int s = 0; s < 4; ++s) {           // k = 32s + 8q + j
        bf16x8 a;
#pragma unroll
        for (int j = 0; j < 8; ++j) a[j] = (__bf16)0.0f;
        if (rowA < NN) a = *(const bf16x8*)(agg + (size_t)rowA * F1 + s * 32 + q * 8);
        const __hip_bfloat16* bp = W1p + ((size_t)(4 * s + q) * F2) * 8;
#pragma unroll
        for (int c = 0; c < 16; ++c) {
            bf16x8 b = *(const bf16x8*)(bp + ((size_t)(c * 16 + m) << 3));
            acc[c] = __builtin_amdgcn_mfma_f32_16x16x32_bf16(a, b, acc[c], 0, 0, 0);
        }
    }

#pragma unroll
    for (int c = 0; c < 16; ++c) {
        int col = c * 16 + m;
        float bj = b1[col];
#pragma unroll
        for (int r = 0; r < 4; ++r) {
            int lr = wave * 16 + q * 4 + r;
            h_s[lr][col] = __float2bfloat16(fmaxf(acc[c][r] + bj, 0.0f));
        }
    }
    __syncthreads();

    f32x4 acc2[3];
#pragma unroll
    for (int c = 0; c < 3; ++c) acc2[c] = (f32x4){0.f, 0.f, 0.f, 0.f};

#pragma unroll
    for (int s = 0; s < 8; ++s) {
        bf16x8 a = *(const bf16x8*)(&h_s[wave * 16 + m][s * 32 + q * 8]);
        const __hip_bfloat16* bp = W2p + ((size_t)(4 * s + q) * 48) * 8;
#pragma unroll
        for (int c = 0; c < 3; ++c) {
            bf16x8 b = *(const bf16x8*)(bp + ((size_t)(c * 16 + m) << 3));
            acc2[c] = __builtin_amdgcn_mfma_f32_16x16x32_bf16(a, b, acc2[c], 0, 0, 0);
        }
    }

#pragma unroll
    for (int c = 0; c < 3; ++c) {
        int col = c * 16 + m;
        if (col < F3) {
#pragma unroll
            for (int r = 0; r < 4; ++r) {
                int grow = i0 + wave * 16 + q * 4 + r;
                if (grow < NN)
                    tg[(size_t)grow * F3 + col] = f2bf(acc2[c][r] * dinv[grow]);
            }
        }
    }
}

// ---- layer-2 pull aggregation: 2 nodes/wave, dword-per-lane over packed 80B rows ----
__global__ __launch_bounds__(256) void k_agg2(const int* __restrict__ cursor,
                                              const int* __restrict__ cnt,
                                              const int* __restrict__ eidx,
                                              const float* __restrict__ dinv,
                                              const unsigned short* __restrict__ tg,
                                              const float* __restrict__ b2,
                                              float* __restrict__ out) {
    const int wave = threadIdx.x >> 6;
    const int lane = threadIdx.x & 63;
    const int h = lane >> 5;                        // which node of the pair
    const int t = lane & 31;                        // dword index in row (t<20 active)
    const int node = blockIdx.x * 8 + wave * 2 + h; // NN%8==0 -> always valid
    const unsigned* __restrict__ tgw = (const unsigned*)tg;
    if (t >= 20) return;                            // 80B row = 20 dwords

    unsigned vs = tgw[(size_t)node * 20 + t];       // self term
    float a0 = bflo(vs), a1 = bfhi(vs);
    const int n = cnt[node];
    const int s = cursor[node] - n;
    int k = 0;
    for (; k + 7 < n; k += 8) {
        int r0 = eidx[s + k + 0], r1 = eidx[s + k + 1];
        int r2 = eidx[s + k + 2], r3 = eidx[s + k + 3];
        int r4 = eidx[s + k + 4], r5 = eidx[s + k + 5];
        int r6 = eidx[s + k + 6], r7 = eidx[s + k + 7];
        unsigned v0 = tgw[(size_t)r0 * 20 + t];
        unsigned v1 = tgw[(size_t)r1 * 20 + t];
        unsigned v2 = tgw[(size_t)r2 * 20 + t];
        unsigned v3 = tgw[(size_t)r3 * 20 + t];
        unsigned v4 = tgw[(size_t)r4 * 20 + t];
        unsigned v5 = tgw[(size_t)r5 * 20 + t];
        unsigned v6 = tgw[(size_t)r6 * 20 + t];
        unsigned v7 = tgw[(size_t)r7 * 20 + t];
        a0 += bflo(v0); a1 += bfhi(v0);
        a0 += bflo(v1); a1 += bfhi(v1);
        a0 += bflo(v2); a1 += bfhi(v2);
        a0 += bflo(v3); a1 += bfhi(v3);
        a0 += bflo(v4); a1 += bfhi(v4);
        a0 += bflo(v5); a1 += bfhi(v5);
        a0 += bflo(v6); a1 += bfhi(v6);
        a0 += bflo(v7); a1 += bfhi(v7);
    }
    for (; k + 3 < n; k += 4) {
        int r0 = eidx[s + k + 0], r1 = eidx[s + k + 1];
        int r2 = eidx[s + k + 2], r3 = eidx[s + k + 3];
        unsigned v0 = tgw[(size_t)r0 * 20 + t];
        unsigned v1 = tgw[(size_t)r1 * 20 + t];
        unsigned v2 = tgw[(size_t)r2 * 20 + t];
        unsigned v3 = tgw[(size_t)r3 * 20 + t];
        a0 += bflo(v0); a1 += bfhi(v0);
        a0 += bflo(v1); a1 += bfhi(v1);
        a0 += bflo(v2); a1 += bfhi(v2);
        a0 += bflo(v3); a1 += bfhi(v3);
    }
    for (; k < n; ++k) {
        unsigned v0 = tgw[(size_t)eidx[s + k] * 20 + t];
        a0 += bflo(v0); a1 += bfhi(v0);
    }
    float d = dinv[node];
    float2 bb = ((const float2*)b2)[t];
    float2 o;
    o.x = a0 * d + bb.x;
    o.y = a1 * d + bb.y;
    ((float2*)(out + (size_t)node * F3))[t] = o;
}

extern "C" void kernel_launch(void* const* d_in, const int* in_sizes, int n_in,
                              void* d_out, int out_size, void* d_ws, size_t ws_size,
                              hipStream_t stream) {
    const float* x  = (const float*)d_in[0];
    const int*   ei = (const int*)d_in[1];
    const float* W1 = (const float*)d_in[2];
    const float* b1 = (const float*)d_in[3];
    const float* W2 = (const float*)d_in[4];
    const float* b2 = (const float*)d_in[5];
    float* out = (float*)d_out;

    const int* row = ei;
    const int* col = ei + EE;

    // ws: cnt[N] | cursor[N] | dinv[N] | bcur[NBUK*BSTR] | pad | eidx[NBUK*DCAP]
    //     | xh[N*64 u32] | agg[N*64 u32] | W1p | W2p        ~59 MB
    // overlays: rec (NBUK*DCAP u32 = 6.4MB) on agg (dead until k_agg1);
    // tg (N*40 bf16 packed, 8MB) on xh (dead after k_agg1; agg1/gemm separate
    // launches — round-4 lesson).
    // ints before eidx: 300000 + 6256 + 8 = 306264 -> byte 1225056 %16==0.
    // ints before xh: 306264 + 1601536 = 1907800 -> byte 7631200 %16==0.
    int* cnt     = (int*)d_ws;
    int* cursor  = cnt + NN;
    float* dinv  = (float*)(cursor + NN);
    int* bcur    = (int*)(dinv + NN);               // stride-16 padded counters
    int* eidx    = bcur + NBUK * BSTR + 8;
    unsigned* xh  = (unsigned*)(eidx + NBUK * DCAP);
    unsigned* agg = xh + (size_t)NN * 64;
    unsigned* rec = agg;                               // overlay on agg (6.4MB)
    unsigned short* tg = (unsigned short*)xh;          // overlay on xh (8MB)
    __hip_bfloat16* W1p = (__hip_bfloat16*)(agg + (size_t)NN * 64);
    __hip_bfloat16* W2p = W1p + (size_t)F1 * F2;

    hipMemsetAsync(bcur, 0, NBUK * BSTR * sizeof(int), stream);
    k_scatA<<<NBLK, 256, 0, stream>>>(row, col, bcur, rec);
    k_csr  <<<NBUK, 256, 0, stream>>>(bcur, rec, eidx, cnt, cursor, dinv);

    k_prep<<<XB2 + WB, 256, 0, stream>>>(
        (const float4*)x, dinv, (uint2*)xh, W1, W2, W1p, W2p);

    k_agg1<<<(NN + 3) / 4, 256, 0, stream>>>(cursor, cnt, eidx, dinv, xh, agg);
    k_gemm_mfma<<<(NN + MROWS - 1) / MROWS, 256, 0, stream>>>(
        (const __hip_bfloat16*)agg, W1p, b1, W2p, dinv, tg);
    k_agg2<<<NN / 8, 256, 0, stream>>>(cursor, cnt, eidx, dinv, tg, b2, out);
}

// Round 10
// 274.561 us; speedup vs baseline: 1.0658x; 1.0658x over previous
//
#include <hip/hip_runtime.h>
#include <hip/hip_bf16.h>

#define NN 100000
#define EE 1200000
#define F1 128
#define F2 256
#define F3 40
#define MROWS 64
#define NBUK ((NN + 255) / 256)          // 391 coarse buckets (256 nodes each)
#define NBLK 256                         // scatter blocks (R7-validated shape)
#define CHUNK ((EE + NBLK - 1) / NBLK)   // 4688 edges per block
#define DCAP 4096                        // fixed slots per bucket (mean 3070, +18 sigma)
#define XB2 ((NN * 32 + 255) / 256)      // 12500 blocks for x-prep (float4 granularity)
#define WB ((F1 * F2 + F2 * 48 + 255) / 256)   // 176 weight-pack blocks

typedef __bf16 bf16x8 __attribute__((ext_vector_type(8)));
typedef float  f32x4  __attribute__((ext_vector_type(4)));

__device__ __forceinline__ unsigned short f2bf(float f) {   // RNE bf16
    unsigned u = __float_as_uint(f);
    return (unsigned short)((u + 0x7fffu + ((u >> 16) & 1u)) >> 16);
}
__device__ __forceinline__ float bflo(unsigned v) { return __uint_as_float(v << 16); }
__device__ __forceinline__ float bfhi(unsigned v) { return __uint_as_float(v & 0xffff0000u); }

// ---- pass 1 (fused hist+reserve+scatter, R7-validated): block LDS-histograms
// its chunk, reserves one contiguous range per bucket (one global atomicAdd per
// (block,bucket)), re-reads row/col (L2-hot) and scatters LDS-cursor-coalesced
// into the bucket's FIXED region rec[bucket*DCAP ...]. ----
__global__ __launch_bounds__(256) void k_scatA(const int* __restrict__ row,
                                               const int* __restrict__ col,
                                               int* __restrict__ bcur,
                                               unsigned* __restrict__ rec) {
    __shared__ int lh[NBUK];     // local count, then local cursor
    __shared__ int lbase[NBUK];  // reserved global base per bucket
    for (int i = threadIdx.x; i < NBUK; i += 256) lh[i] = 0;
    __syncthreads();
    const int e0 = blockIdx.x * CHUNK;
    const int e1 = min(e0 + CHUNK, EE);
    for (int e = e0 + threadIdx.x; e < e1; e += 256) {
        int c = col[e];
        if ((unsigned)c < (unsigned)NN) atomicAdd(&lh[c >> 8], 1);
    }
    __syncthreads();
    for (int i = threadIdx.x; i < NBUK; i += 256) {
        int cn = lh[i];
        lbase[i] = cn ? atomicAdd(&bcur[i], cn) : 0;   // range reservation
        lh[i] = 0;                                     // reuse as cursor
    }
    __syncthreads();
    for (int e = e0 + threadIdx.x; e < e1; e += 256) {
        int r = row[e], c = col[e];                    // col re-read hits L1/L2
        if ((unsigned)c < (unsigned)NN) {
            int b = c >> 8;
            int pos = lbase[b] + atomicAdd(&lh[b], 1); // LDS atomic
            if (pos < DCAP)
                rec[(size_t)b * DCAP + pos] =
                    ((unsigned)r & 0xFFFFFFu) | ((unsigned)(c & 255) << 24);
        }
    }
}

// ---- pass 2: bucket -> CSR; rec chunk cached in LDS (single global read);
// cnt via LDS histogram; cursor(end)=b*DCAP+excl+cnt; dinv. ----
__global__ __launch_bounds__(256) void k_csr(const int* __restrict__ bcur,
                                             const unsigned* __restrict__ rec,
                                             int* __restrict__ eidx,
                                             int* __restrict__ cnt,
                                             int* __restrict__ cursor,
                                             float* __restrict__ dinv) {
    __shared__ int lcnt[256];
    __shared__ int s[256];
    __shared__ int lcur[256];
    __shared__ unsigned lrec[DCAP];   // 16 KB cached records
    __shared__ int lde[DCAP];         // 16 KB sorted rows
    const int b = blockIdx.x;
    const int tid = threadIdx.x;
    lcnt[tid] = 0;
    __syncthreads();
    const int base = b * DCAP;
    const int nb = min(bcur[b], DCAP);
    for (int j = tid; j < nb; j += 256) {
        unsigned v = rec[(size_t)base + j];
        lrec[j] = v;
        atomicAdd(&lcnt[v >> 24], 1);
    }
    __syncthreads();
    int cv = lcnt[tid];
    s[tid] = cv;
    __syncthreads();
    int acc = cv;
    for (int d = 1; d < 256; d <<= 1) {
        int add = (tid >= d) ? s[tid - d] : 0;
        __syncthreads();
        acc += add;
        s[tid] = acc;
        __syncthreads();
    }
    int excl = acc - cv;
    lcur[tid] = excl;
    const int node = (b << 8) + tid;
    if (node < NN) {
        cnt[node] = cv;
        cursor[node] = base + excl + cv;            // END cursor (start = end - cnt)
        dinv[node] = rsqrtf((float)(cv + 1));       // +1 self-loop
    }
    __syncthreads();
    for (int j = tid; j < nb; j += 256) {
        unsigned v = lrec[j];
        int pos = atomicAdd(&lcur[v >> 24], 1);     // LDS atomic
        lde[pos] = (int)(v & 0xFFFFFFu);
    }
    __syncthreads();
    for (int j = tid; j < nb; j += 256) eidx[base + j] = lde[j];
}

// ---- fused prep: xh[i] = bf16(x[i]*dinv[i]) ; pack W1,W2. float4-vectorized ----
__global__ void k_prep(const float4* __restrict__ x, const float* __restrict__ dinv,
                       uint2* __restrict__ xh,
                       const float* __restrict__ W1, const float* __restrict__ W2,
                       __hip_bfloat16* __restrict__ W1p, __hip_bfloat16* __restrict__ W2p) {
    if (blockIdx.x < XB2) {
        int idx = blockIdx.x * 256 + threadIdx.x;   // NN*32 float4s, exact multiple
        float d = dinv[idx >> 5];
        float4 v = x[idx];
        uint2 o;
        o.x = (unsigned)f2bf(v.x * d) | ((unsigned)f2bf(v.y * d) << 16);
        o.y = (unsigned)f2bf(v.z * d) | ((unsigned)f2bf(v.w * d) << 16);
        xh[idx] = o;
    } else {
        int idx = (blockIdx.x - XB2) * 256 + threadIdx.x;
        if (idx < F1 * F2) {
            int k = idx / F2, col = idx - (idx / F2) * F2;
            int k8 = k >> 3, j = k & 7;
            W1p[((size_t)(k8 * F2 + col) << 3) + j] = __float2bfloat16(W1[(size_t)k * F2 + col]);
        } else if (idx < F1 * F2 + F2 * 48) {
            int i2 = idx - F1 * F2;
            int k = i2 / 48, col = i2 - (i2 / 48) * 48;
            int k8 = k >> 3, j = k & 7;
            float v = (col < F3) ? W2[(size_t)k * F3 + col] : 0.0f;
            W2p[((size_t)(k8 * 48 + col) << 3) + j] = __float2bfloat16(v);
        }
    }
}

// ---- layer-1 pull aggregation: known-good structure (3.65 TB/s, 71% occ) ----
__global__ __launch_bounds__(256) void k_agg1(const int* __restrict__ cursor,
                                              const int* __restrict__ cnt,
                                              const int* __restrict__ eidx,
                                              const float* __restrict__ dinv,
                                              const unsigned* __restrict__ xh,
                                              unsigned* __restrict__ agg) {
    int node = blockIdx.x * 4 + (threadIdx.x >> 6);
    int lane = threadIdx.x & 63;
    if (node >= NN) return;
    unsigned vs = xh[((size_t)node << 6) + lane];
    float a0 = bflo(vs), a1 = bfhi(vs);
    int n = cnt[node];
    int s = cursor[node] - n;
    int k = 0;
    for (; k + 7 < n; k += 8) {
        int r0 = eidx[s + k + 0], r1 = eidx[s + k + 1];
        int r2 = eidx[s + k + 2], r3 = eidx[s + k + 3];
        int r4 = eidx[s + k + 4], r5 = eidx[s + k + 5];
        int r6 = eidx[s + k + 6], r7 = eidx[s + k + 7];
        unsigned v0 = xh[((size_t)r0 << 6) + lane];
        unsigned v1 = xh[((size_t)r1 << 6) + lane];
        unsigned v2 = xh[((size_t)r2 << 6) + lane];
        unsigned v3 = xh[((size_t)r3 << 6) + lane];
        unsigned v4 = xh[((size_t)r4 << 6) + lane];
        unsigned v5 = xh[((size_t)r5 << 6) + lane];
        unsigned v6 = xh[((size_t)r6 << 6) + lane];
        unsigned v7 = xh[((size_t)r7 << 6) + lane];
        a0 += bflo(v0); a1 += bfhi(v0);
        a0 += bflo(v1); a1 += bfhi(v1);
        a0 += bflo(v2); a1 += bfhi(v2);
        a0 += bflo(v3); a1 += bfhi(v3);
        a0 += bflo(v4); a1 += bfhi(v4);
        a0 += bflo(v5); a1 += bfhi(v5);
        a0 += bflo(v6); a1 += bfhi(v6);
        a0 += bflo(v7); a1 += bfhi(v7);
    }
    for (; k + 3 < n; k += 4) {
        int r0 = eidx[s + k + 0], r1 = eidx[s + k + 1];
        int r2 = eidx[s + k + 2], r3 = eidx[s + k + 3];
        unsigned v0 = xh[((size_t)r0 << 6) + lane];
        unsigned v1 = xh[((size_t)r1 << 6) + lane];
        unsigned v2 = xh[((size_t)r2 << 6) + lane];
        unsigned v3 = xh[((size_t)r3 << 6) + lane];
        a0 += bflo(v0); a1 += bfhi(v0);
        a0 += bflo(v1); a1 += bfhi(v1);
        a0 += bflo(v2); a1 += bfhi(v2);
        a0 += bflo(v3); a1 += bfhi(v3);
    }
    for (; k < n; ++k) {
        unsigned v0 = xh[((size_t)eidx[s + k] << 6) + lane];
        a0 += bflo(v0); a1 += bfhi(v0);
    }
    float d = dinv[node];
    agg[((size_t)node << 6) + lane] = (unsigned)f2bf(a0 * d) | ((unsigned)f2bf(a1 * d) << 16);
}

// ---- fused MFMA GEMM1 + ReLU + GEMM2; tg rows PACKED to 40 bf16 (80B, 16B-aligned) ----
__global__ __launch_bounds__(256) void k_gemm_mfma(
    const __hip_bfloat16* __restrict__ agg, const __hip_bfloat16* __restrict__ W1p,
    const float* __restrict__ b1, const __hip_bfloat16* __restrict__ W2p,
    const float* __restrict__ dinv, unsigned short* __restrict__ tg) {
    __shared__ __hip_bfloat16 h_s[MROWS][F2 + 8];   // 33 KB
    const int i0   = blockIdx.x * MROWS;
    const int wave = threadIdx.x >> 6;
    const int lane = threadIdx.x & 63;
    const int m = lane & 15, q = lane >> 4;
    const int rowA = i0 + wave * 16 + m;

    f32x4 acc[16];
#pragma unroll
    for (int c = 0; c < 16; ++c) acc[c] = (f32x4){0.f, 0.f, 0.f, 0.f};

#pragma unroll
    for (int s = 0; s < 4; ++s) {           // k = 32s + 8q + j
        bf16x8 a;
#pragma unroll
        for (int j = 0; j < 8; ++j) a[j] = (__bf16)0.0f;
        if (rowA < NN) a = *(const bf16x8*)(agg + (size_t)rowA * F1 + s * 32 + q * 8);
        const __hip_bfloat16* bp = W1p + ((size_t)(4 * s + q) * F2) * 8;
#pragma unroll
        for (int c = 0; c < 16; ++c) {
            bf16x8 b = *(const bf16x8*)(bp + ((size_t)(c * 16 + m) << 3));
            acc[c] = __builtin_amdgcn_mfma_f32_16x16x32_bf16(a, b, acc[c], 0, 0, 0);
        }
    }

#pragma unroll
    for (int c = 0; c < 16; ++c) {
        int col = c * 16 + m;
        float bj = b1[col];
#pragma unroll
        for (int r = 0; r < 4; ++r) {
            int lr = wave * 16 + q * 4 + r;
            h_s[lr][col] = __float2bfloat16(fmaxf(acc[c][r] + bj, 0.0f));
        }
    }
    __syncthreads();

    f32x4 acc2[3];
#pragma unroll
    for (int c = 0; c < 3; ++c) acc2[c] = (f32x4){0.f, 0.f, 0.f, 0.f};

#pragma unroll
    for (int s = 0; s < 8; ++s) {
        bf16x8 a = *(const bf16x8*)(&h_s[wave * 16 + m][s * 32 + q * 8]);
        const __hip_bfloat16* bp = W2p + ((size_t)(4 * s + q) * 48) * 8;
#pragma unroll
        for (int c = 0; c < 3; ++c) {
            bf16x8 b = *(const bf16x8*)(bp + ((size_t)(c * 16 + m) << 3));
            acc2[c] = __builtin_amdgcn_mfma_f32_16x16x32_bf16(a, b, acc2[c], 0, 0, 0);
        }
    }

#pragma unroll
    for (int c = 0; c < 3; ++c) {
        int col = c * 16 + m;
        if (col < F3) {
#pragma unroll
            for (int r = 0; r < 4; ++r) {
                int grow = i0 + wave * 16 + q * 4 + r;
                if (grow < NN)
                    tg[(size_t)grow * F3 + col] = f2bf(acc2[c][r] * dinv[grow]);
            }
        }
    }
}

// ---- layer-2 pull aggregation, v2: 6 nodes per wave (one per 10-lane group),
// uint2 (8B) per lane over packed 80B rows -> 6 rows x 8-deep = 3.8KB in
// flight per wave (3x the old 2-node/dword design), 60/64 lanes active.
// No shuffles/barriers; lanes 60-63 exit early. ----
__global__ __launch_bounds__(256) void k_agg2(const int* __restrict__ cursor,
                                              const int* __restrict__ cnt,
                                              const int* __restrict__ eidx,
                                              const float* __restrict__ dinv,
                                              const unsigned short* __restrict__ tg,
                                              const float* __restrict__ b2,
                                              float* __restrict__ out) {
    const int wave = threadIdx.x >> 6;
    const int lane = threadIdx.x & 63;
    const int g = lane / 10;                        // 0..6 (6 => idle)
    const int t = lane - g * 10;                    // uint2 index in row
    const int node = blockIdx.x * 24 + wave * 6 + g;
    if (g >= 6 || node >= NN) return;
    const uint2* __restrict__ tg2 = (const uint2*)tg;

    uint2 v = tg2[(size_t)node * 10 + t];           // self term
    float a0 = bflo(v.x), a1 = bfhi(v.x), a2 = bflo(v.y), a3 = bfhi(v.y);
    const int n = cnt[node];
    const int s = cursor[node] - n;
    int k = 0;
    for (; k + 7 < n; k += 8) {
        int r0 = eidx[s + k + 0], r1 = eidx[s + k + 1];
        int r2 = eidx[s + k + 2], r3 = eidx[s + k + 3];
        int r4 = eidx[s + k + 4], r5 = eidx[s + k + 5];
        int r6 = eidx[s + k + 6], r7 = eidx[s + k + 7];
        uint2 v0 = tg2[(size_t)r0 * 10 + t];
        uint2 v1 = tg2[(size_t)r1 * 10 + t];
        uint2 v2 = tg2[(size_t)r2 * 10 + t];
        uint2 v3 = tg2[(size_t)r3 * 10 + t];
        uint2 v4 = tg2[(size_t)r4 * 10 + t];
        uint2 v5 = tg2[(size_t)r5 * 10 + t];
        uint2 v6 = tg2[(size_t)r6 * 10 + t];
        uint2 v7 = tg2[(size_t)r7 * 10 + t];
        a0 += bflo(v0.x); a1 += bfhi(v0.x); a2 += bflo(v0.y); a3 += bfhi(v0.y);
        a0 += bflo(v1.x); a1 += bfhi(v1.x); a2 += bflo(v1.y); a3 += bfhi(v1.y);
        a0 += bflo(v2.x); a1 += bfhi(v2.x); a2 += bflo(v2.y); a3 += bfhi(v2.y);
        a0 += bflo(v3.x); a1 += bfhi(v3.x); a2 += bflo(v3.y); a3 += bfhi(v3.y);
        a0 += bflo(v4.x); a1 += bfhi(v4.x); a2 += bflo(v4.y); a3 += bfhi(v4.y);
        a0 += bflo(v5.x); a1 += bfhi(v5.x); a2 += bflo(v5.y); a3 += bfhi(v5.y);
        a0 += bflo(v6.x); a1 += bfhi(v6.x); a2 += bflo(v6.y); a3 += bfhi(v6.y);
        a0 += bflo(v7.x); a1 += bfhi(v7.x); a2 += bflo(v7.y); a3 += bfhi(v7.y);
    }
    for (; k + 3 < n; k += 4) {
        int r0 = eidx[s + k + 0], r1 = eidx[s + k + 1];
        int r2 = eidx[s + k + 2], r3 = eidx[s + k + 3];
        uint2 v0 = tg2[(size_t)r0 * 10 + t];
        uint2 v1 = tg2[(size_t)r1 * 10 + t];
        uint2 v2 = tg2[(size_t)r2 * 10 + t];
        uint2 v3 = tg2[(size_t)r3 * 10 + t];
        a0 += bflo(v0.x); a1 += bfhi(v0.x); a2 += bflo(v0.y); a3 += bfhi(v0.y);
        a0 += bflo(v1.x); a1 += bfhi(v1.x); a2 += bflo(v1.y); a3 += bfhi(v1.y);
        a0 += bflo(v2.x); a1 += bfhi(v2.x); a2 += bflo(v2.y); a3 += bfhi(v2.y);
        a0 += bflo(v3.x); a1 += bfhi(v3.x); a2 += bflo(v3.y); a3 += bfhi(v3.y);
    }
    for (; k < n; ++k) {
        uint2 v0 = tg2[(size_t)eidx[s + k] * 10 + t];
        a0 += bflo(v0.x); a1 += bfhi(v0.x); a2 += bflo(v0.y); a3 += bfhi(v0.y);
    }
    float d = dinv[node];
    float4 bb = *(const float4*)(b2 + 4 * t);
    float4 o;
    o.x = a0 * d + bb.x;
    o.y = a1 * d + bb.y;
    o.z = a2 * d + bb.z;
    o.w = a3 * d + bb.w;
    *(float4*)(out + (size_t)node * F3 + 4 * t) = o;
}

extern "C" void kernel_launch(void* const* d_in, const int* in_sizes, int n_in,
                              void* d_out, int out_size, void* d_ws, size_t ws_size,
                              hipStream_t stream) {
    const float* x  = (const float*)d_in[0];
    const int*   ei = (const int*)d_in[1];
    const float* W1 = (const float*)d_in[2];
    const float* b1 = (const float*)d_in[3];
    const float* W2 = (const float*)d_in[4];
    const float* b2 = (const float*)d_in[5];
    float* out = (float*)d_out;

    const int* row = ei;
    const int* col = ei + EE;

    // ws: cnt[N] | cursor[N] | dinv[N] | bcur[NBUK] | pad | eidx[NBUK*DCAP]
    //     | xh[N*64 u32] | agg[N*64 u32] | W1p | W2p        ~59 MB
    // overlays: rec (NBUK*DCAP u32 = 6.4MB) on agg (dead until k_agg1);
    // tg (N*40 bf16 packed, 8MB) on xh (dead after k_agg1; agg1/gemm separate
    // launches — round-4 lesson).
    // ints before eidx: 3*100000 + 391 + 9 = 300400 -> eidx 16B-aligned;
    // ints before xh: 300400 + 1601536 = 1901936 -> xh byte 7607744 %16==0.
    int* cnt     = (int*)d_ws;
    int* cursor  = cnt + NN;
    float* dinv  = (float*)(cursor + NN);
    int* bcur    = (int*)(dinv + NN);
    int* eidx    = bcur + NBUK + 9;            // pad -> 16B alignment
    unsigned* xh  = (unsigned*)(eidx + NBUK * DCAP);
    unsigned* agg = xh + (size_t)NN * 64;
    unsigned* rec = agg;                               // overlay on agg (6.4MB)
    unsigned short* tg = (unsigned short*)xh;          // overlay on xh (8MB)
    __hip_bfloat16* W1p = (__hip_bfloat16*)(agg + (size_t)NN * 64);
    __hip_bfloat16* W2p = W1p + (size_t)F1 * F2;

    hipMemsetAsync(bcur, 0, NBUK * sizeof(int), stream);
    k_scatA<<<NBLK, 256, 0, stream>>>(row, col, bcur, rec);
    k_csr  <<<NBUK, 256, 0, stream>>>(bcur, rec, eidx, cnt, cursor, dinv);

    k_prep<<<XB2 + WB, 256, 0, stream>>>(
        (const float4*)x, dinv, (uint2*)xh, W1, W2, W1p, W2p);

    k_agg1<<<(NN + 3) / 4, 256, 0, stream>>>(cursor, cnt, eidx, dinv, xh, agg);
    k_gemm_mfma<<<(NN + MROWS - 1) / MROWS, 256, 0, stream>>>(
        (const __hip_bfloat16*)agg, W1p, b1, W2p, dinv, tg);
    k_agg2<<<(NN + 23) / 24, 256, 0, stream>>>(cursor, cnt, eidx, dinv, tg, b2, out);
}

// Round 11
// 266.650 us; speedup vs baseline: 1.0974x; 1.0297x over previous
//
#include <hip/hip_runtime.h>
#include <hip/hip_bf16.h>

#define NN 100000
#define EE 1200000
#define F1 128
#define F2 256
#define F3 40
#define MROWS 64
#define NBUK ((NN + 255) / 256)          // 391 coarse buckets (256 nodes each)
#define NBLK 256                         // scatter blocks (R7-validated shape)
#define CHUNK ((EE + NBLK - 1) / NBLK)   // 4688 edges per block
#define DCAP 4096                        // fixed slots per bucket (mean 3070, +18 sigma)
#define XB2 ((NN * 32 + 255) / 256)      // 12500 blocks for x-prep (float4 granularity)
#define WB ((F1 * F2 + F2 * 48 + 255) / 256)   // 176 weight-pack blocks

typedef __bf16 bf16x8 __attribute__((ext_vector_type(8)));
typedef float  f32x4  __attribute__((ext_vector_type(4)));

__device__ __forceinline__ unsigned short f2bf(float f) {   // RNE bf16
    unsigned u = __float_as_uint(f);
    return (unsigned short)((u + 0x7fffu + ((u >> 16) & 1u)) >> 16);
}
__device__ __forceinline__ float bflo(unsigned v) { return __uint_as_float(v << 16); }
__device__ __forceinline__ float bfhi(unsigned v) { return __uint_as_float(v & 0xffff0000u); }

// ---- launch 1 (scatA ∥ prep): blocks [0,NBLK) run the R7-validated
// hist+reserve+scatter; blocks [NBLK, NBLK+XB2) stream x -> bf16 xh UNSCALED
// (dinv applied later in agg1 as FMA — removes the prep->csr dependency);
// remaining WB blocks pack W1/W2. The streaming blocks fill CU idle time
// under scatA's latency/atomic-bound phases. ----
__global__ __launch_bounds__(256) void k_scatprep(
    const int* __restrict__ row, const int* __restrict__ col,
    int* __restrict__ bcur, unsigned* __restrict__ rec,
    const float4* __restrict__ x, uint2* __restrict__ xh,
    const float* __restrict__ W1, const float* __restrict__ W2,
    __hip_bfloat16* __restrict__ W1p, __hip_bfloat16* __restrict__ W2p) {
    if (blockIdx.x < NBLK) {
        __shared__ int lh[NBUK];     // local count, then local cursor
        __shared__ int lbase[NBUK];  // reserved global base per bucket
        for (int i = threadIdx.x; i < NBUK; i += 256) lh[i] = 0;
        __syncthreads();
        const int e0 = blockIdx.x * CHUNK;
        const int e1 = min(e0 + CHUNK, EE);
        for (int e = e0 + threadIdx.x; e < e1; e += 256) {
            int c = col[e];
            if ((unsigned)c < (unsigned)NN) atomicAdd(&lh[c >> 8], 1);
        }
        __syncthreads();
        for (int i = threadIdx.x; i < NBUK; i += 256) {
            int cn = lh[i];
            lbase[i] = cn ? atomicAdd(&bcur[i], cn) : 0;   // range reservation
            lh[i] = 0;                                     // reuse as cursor
        }
        __syncthreads();
        for (int e = e0 + threadIdx.x; e < e1; e += 256) {
            int r = row[e], c = col[e];                    // col re-read hits L1/L2
            if ((unsigned)c < (unsigned)NN) {
                int b = c >> 8;
                int pos = lbase[b] + atomicAdd(&lh[b], 1); // LDS atomic
                if (pos < DCAP)
                    rec[(size_t)b * DCAP + pos] =
                        ((unsigned)r & 0xFFFFFFu) | ((unsigned)(c & 255) << 24);
            }
        }
    } else if (blockIdx.x < NBLK + XB2) {
        int idx = (blockIdx.x - NBLK) * 256 + threadIdx.x;  // NN*32 float4s exact
        float4 v = x[idx];
        uint2 o;
        o.x = (unsigned)f2bf(v.x) | ((unsigned)f2bf(v.y) << 16);
        o.y = (unsigned)f2bf(v.z) | ((unsigned)f2bf(v.w) << 16);
        xh[idx] = o;
    } else {
        int idx = (blockIdx.x - NBLK - XB2) * 256 + threadIdx.x;
        if (idx < F1 * F2) {
            int k = idx / F2, c = idx - (idx / F2) * F2;
            int k8 = k >> 3, j = k & 7;
            W1p[((size_t)(k8 * F2 + c) << 3) + j] = __float2bfloat16(W1[(size_t)k * F2 + c]);
        } else {                               // grid exact: idx < F1*F2 + F2*48
            int i2 = idx - F1 * F2;
            int k = i2 / 48, c = i2 - (i2 / 48) * 48;
            int k8 = k >> 3, j = k & 7;
            float v = (c < F3) ? W2[(size_t)k * F3 + c] : 0.0f;
            W2p[((size_t)(k8 * 48 + c) << 3) + j] = __float2bfloat16(v);
        }
    }
}

// ---- pass 2: bucket -> CSR; rec chunk cached in LDS (single global read);
// cnt via LDS histogram; cursor(end)=b*DCAP+excl+cnt; dinv. ----
__global__ __launch_bounds__(256) void k_csr(const int* __restrict__ bcur,
                                             const unsigned* __restrict__ rec,
                                             int* __restrict__ eidx,
                                             int* __restrict__ cnt,
                                             int* __restrict__ cursor,
                                             float* __restrict__ dinv) {
    __shared__ int lcnt[256];
    __shared__ int s[256];
    __shared__ int lcur[256];
    __shared__ unsigned lrec[DCAP];   // 16 KB cached records
    __shared__ int lde[DCAP];         // 16 KB sorted rows
    const int b = blockIdx.x;
    const int tid = threadIdx.x;
    lcnt[tid] = 0;
    __syncthreads();
    const int base = b * DCAP;
    const int nb = min(bcur[b], DCAP);
    for (int j = tid; j < nb; j += 256) {
        unsigned v = rec[(size_t)base + j];
        lrec[j] = v;
        atomicAdd(&lcnt[v >> 24], 1);
    }
    __syncthreads();
    int cv = lcnt[tid];
    s[tid] = cv;
    __syncthreads();
    int acc = cv;
    for (int d = 1; d < 256; d <<= 1) {
        int add = (tid >= d) ? s[tid - d] : 0;
        __syncthreads();
        acc += add;
        s[tid] = acc;
        __syncthreads();
    }
    int excl = acc - cv;
    lcur[tid] = excl;
    const int node = (b << 8) + tid;
    if (node < NN) {
        cnt[node] = cv;
        cursor[node] = base + excl + cv;            // END cursor (start = end - cnt)
        dinv[node] = rsqrtf((float)(cv + 1));       // +1 self-loop
    }
    __syncthreads();
    for (int j = tid; j < nb; j += 256) {
        unsigned v = lrec[j];
        int pos = atomicAdd(&lcur[v >> 24], 1);     // LDS atomic
        lde[pos] = (int)(v & 0xFFFFFFu);
    }
    __syncthreads();
    for (int j = tid; j < nb; j += 256) eidx[base + j] = lde[j];
}

// ---- layer-1 pull aggregation (xh unscaled -> per-row dinv FMA; same VALU
// count as the add version: v_fmac vs v_add. dinv[r] loads are wave-uniform
// broadcasts, L2-resident (400 KB). ----
__global__ __launch_bounds__(256) void k_agg1(const int* __restrict__ cursor,
                                              const int* __restrict__ cnt,
                                              const int* __restrict__ eidx,
                                              const float* __restrict__ dinv,
                                              const unsigned* __restrict__ xh,
                                              unsigned* __restrict__ agg) {
    int node = blockIdx.x * 4 + (threadIdx.x >> 6);
    int lane = threadIdx.x & 63;
    if (node >= NN) return;
    float dn = dinv[node];
    unsigned vs = xh[((size_t)node << 6) + lane];
    float a0 = bflo(vs) * dn, a1 = bfhi(vs) * dn;   // self-loop: x[node]*dinv[node]
    int n = cnt[node];
    int s = cursor[node] - n;
    int k = 0;
    for (; k + 7 < n; k += 8) {
        int r0 = eidx[s + k + 0], r1 = eidx[s + k + 1];
        int r2 = eidx[s + k + 2], r3 = eidx[s + k + 3];
        int r4 = eidx[s + k + 4], r5 = eidx[s + k + 5];
        int r6 = eidx[s + k + 6], r7 = eidx[s + k + 7];
        float d0 = dinv[r0], d1 = dinv[r1], d2 = dinv[r2], d3 = dinv[r3];
        float d4 = dinv[r4], d5 = dinv[r5], d6 = dinv[r6], d7 = dinv[r7];
        unsigned v0 = xh[((size_t)r0 << 6) + lane];
        unsigned v1 = xh[((size_t)r1 << 6) + lane];
        unsigned v2 = xh[((size_t)r2 << 6) + lane];
        unsigned v3 = xh[((size_t)r3 << 6) + lane];
        unsigned v4 = xh[((size_t)r4 << 6) + lane];
        unsigned v5 = xh[((size_t)r5 << 6) + lane];
        unsigned v6 = xh[((size_t)r6 << 6) + lane];
        unsigned v7 = xh[((size_t)r7 << 6) + lane];
        a0 += bflo(v0) * d0; a1 += bfhi(v0) * d0;
        a0 += bflo(v1) * d1; a1 += bfhi(v1) * d1;
        a0 += bflo(v2) * d2; a1 += bfhi(v2) * d2;
        a0 += bflo(v3) * d3; a1 += bfhi(v3) * d3;
        a0 += bflo(v4) * d4; a1 += bfhi(v4) * d4;
        a0 += bflo(v5) * d5; a1 += bfhi(v5) * d5;
        a0 += bflo(v6) * d6; a1 += bfhi(v6) * d6;
        a0 += bflo(v7) * d7; a1 += bfhi(v7) * d7;
    }
    for (; k + 3 < n; k += 4) {
        int r0 = eidx[s + k + 0], r1 = eidx[s + k + 1];
        int r2 = eidx[s + k + 2], r3 = eidx[s + k + 3];
        float d0 = dinv[r0], d1 = dinv[r1], d2 = dinv[r2], d3 = dinv[r3];
        unsigned v0 = xh[((size_t)r0 << 6) + lane];
        unsigned v1 = xh[((size_t)r1 << 6) + lane];
        unsigned v2 = xh[((size_t)r2 << 6) + lane];
        unsigned v3 = xh[((size_t)r3 << 6) + lane];
        a0 += bflo(v0) * d0; a1 += bfhi(v0) * d0;
        a0 += bflo(v1) * d1; a1 += bfhi(v1) * d1;
        a0 += bflo(v2) * d2; a1 += bfhi(v2) * d2;
        a0 += bflo(v3) * d3; a1 += bfhi(v3) * d3;
    }
    for (; k < n; ++k) {
        int r0 = eidx[s + k];
        float d0 = dinv[r0];
        unsigned v0 = xh[((size_t)r0 << 6) + lane];
        a0 += bflo(v0) * d0; a1 += bfhi(v0) * d0;
    }
    agg[((size_t)node << 6) + lane] = (unsigned)f2bf(a0 * dn) | ((unsigned)f2bf(a1 * dn) << 16);
}

// ---- fused MFMA GEMM1 + ReLU + GEMM2; tg rows PACKED to 40 bf16 (80B, 16B-aligned) ----
__global__ __launch_bounds__(256) void k_gemm_mfma(
    const __hip_bfloat16* __restrict__ agg, const __hip_bfloat16* __restrict__ W1p,
    const float* __restrict__ b1, const __hip_bfloat16* __restrict__ W2p,
    const float* __restrict__ dinv, unsigned short* __restrict__ tg) {
    __shared__ __hip_bfloat16 h_s[MROWS][F2 + 8];   // 33 KB
    const int i0   = blockIdx.x * MROWS;
    const int wave = threadIdx.x >> 6;
    const int lane = threadIdx.x & 63;
    const int m = lane & 15, q = lane >> 4;
    const int rowA = i0 + wave * 16 + m;

    f32x4 acc[16];
#pragma unroll
    for (int c = 0; c < 16; ++c) acc[c] = (f32x4){0.f, 0.f, 0.f, 0.f};

#pragma unroll
    for (int s = 0; s < 4; ++s) {           // k = 32s + 8q + j
        bf16x8 a;
#pragma unroll
        for (int j = 0; j < 8; ++j) a[j] = (__bf16)0.0f;
        if (rowA < NN) a = *(const bf16x8*)(agg + (size_t)rowA * F1 + s * 32 + q * 8);
        const __hip_bfloat16* bp = W1p + ((size_t)(4 * s + q) * F2) * 8;
#pragma unroll
        for (int c = 0; c < 16; ++c) {
            bf16x8 b = *(const bf16x8*)(bp + ((size_t)(c * 16 + m) << 3));
            acc[c] = __builtin_amdgcn_mfma_f32_16x16x32_bf16(a, b, acc[c], 0, 0, 0);
        }
    }

#pragma unroll
    for (int c = 0; c < 16; ++c) {
        int col = c * 16 + m;
        float bj = b1[col];
#pragma unroll
        for (int r = 0; r < 4; ++r) {
            int lr = wave * 16 + q * 4 + r;
            h_s[lr][col] = __float2bfloat16(fmaxf(acc[c][r] + bj, 0.0f));
        }
    }
    __syncthreads();

    f32x4 acc2[3];
#pragma unroll
    for (int c = 0; c < 3; ++c) acc2[c] = (f32x4){0.f, 0.f, 0.f, 0.f};

#pragma unroll
    for (int s = 0; s < 8; ++s) {
        bf16x8 a = *(const bf16x8*)(&h_s[wave * 16 + m][s * 32 + q * 8]);
        const __hip_bfloat16* bp = W2p + ((size_t)(4 * s + q) * 48) * 8;
#pragma unroll
        for (int c = 0; c < 3; ++c) {
            bf16x8 b = *(const bf16x8*)(bp + ((size_t)(c * 16 + m) << 3));
            acc2[c] = __builtin_amdgcn_mfma_f32_16x16x32_bf16(a, b, acc2[c], 0, 0, 0);
        }
    }

#pragma unroll
    for (int c = 0; c < 3; ++c) {
        int col = c * 16 + m;
        if (col < F3) {
#pragma unroll
            for (int r = 0; r < 4; ++r) {
                int grow = i0 + wave * 16 + q * 4 + r;
                if (grow < NN)
                    tg[(size_t)grow * F3 + col] = f2bf(acc2[c][r] * dinv[grow]);
            }
        }
    }
}

// ---- layer-2 pull aggregation: 6 nodes/wave (10-lane groups), uint2 per lane
// over packed 80B rows; 3.8KB in flight per wave (R10-validated). ----
__global__ __launch_bounds__(256) void k_agg2(const int* __restrict__ cursor,
                                              const int* __restrict__ cnt,
                                              const int* __restrict__ eidx,
                                              const float* __restrict__ dinv,
                                              const unsigned short* __restrict__ tg,
                                              const float* __restrict__ b2,
                                              float* __restrict__ out) {
    const int wave = threadIdx.x >> 6;
    const int lane = threadIdx.x & 63;
    const int g = lane / 10;                        // 0..6 (6 => idle)
    const int t = lane - g * 10;                    // uint2 index in row
    const int node = blockIdx.x * 24 + wave * 6 + g;
    if (g >= 6 || node >= NN) return;
    const uint2* __restrict__ tg2 = (const uint2*)tg;

    uint2 v = tg2[(size_t)node * 10 + t];           // self term
    float a0 = bflo(v.x), a1 = bfhi(v.x), a2 = bflo(v.y), a3 = bfhi(v.y);
    const int n = cnt[node];
    const int s = cursor[node] - n;
    int k = 0;
    for (; k + 7 < n; k += 8) {
        int r0 = eidx[s + k + 0], r1 = eidx[s + k + 1];
        int r2 = eidx[s + k + 2], r3 = eidx[s + k + 3];
        int r4 = eidx[s + k + 4], r5 = eidx[s + k + 5];
        int r6 = eidx[s + k + 6], r7 = eidx[s + k + 7];
        uint2 v0 = tg2[(size_t)r0 * 10 + t];
        uint2 v1 = tg2[(size_t)r1 * 10 + t];
        uint2 v2 = tg2[(size_t)r2 * 10 + t];
        uint2 v3 = tg2[(size_t)r3 * 10 + t];
        uint2 v4 = tg2[(size_t)r4 * 10 + t];
        uint2 v5 = tg2[(size_t)r5 * 10 + t];
        uint2 v6 = tg2[(size_t)r6 * 10 + t];
        uint2 v7 = tg2[(size_t)r7 * 10 + t];
        a0 += bflo(v0.x); a1 += bfhi(v0.x); a2 += bflo(v0.y); a3 += bfhi(v0.y);
        a0 += bflo(v1.x); a1 += bfhi(v1.x); a2 += bflo(v1.y); a3 += bfhi(v1.y);
        a0 += bflo(v2.x); a1 += bfhi(v2.x); a2 += bflo(v2.y); a3 += bfhi(v2.y);
        a0 += bflo(v3.x); a1 += bfhi(v3.x); a2 += bflo(v3.y); a3 += bfhi(v3.y);
        a0 += bflo(v4.x); a1 += bfhi(v4.x); a2 += bflo(v4.y); a3 += bfhi(v4.y);
        a0 += bflo(v5.x); a1 += bfhi(v5.x); a2 += bflo(v5.y); a3 += bfhi(v5.y);
        a0 += bflo(v6.x); a1 += bfhi(v6.x); a2 += bflo(v6.y); a3 += bfhi(v6.y);
        a0 += bflo(v7.x); a1 += bfhi(v7.x); a2 += bflo(v7.y); a3 += bfhi(v7.y);
    }
    for (; k + 3 < n; k += 4) {
        int r0 = eidx[s + k + 0], r1 = eidx[s + k + 1];
        int r2 = eidx[s + k + 2], r3 = eidx[s + k + 3];
        uint2 v0 = tg2[(size_t)r0 * 10 + t];
        uint2 v1 = tg2[(size_t)r1 * 10 + t];
        uint2 v2 = tg2[(size_t)r2 * 10 + t];
        uint2 v3 = tg2[(size_t)r3 * 10 + t];
        a0 += bflo(v0.x); a1 += bfhi(v0.x); a2 += bflo(v0.y); a3 += bfhi(v0.y);
        a0 += bflo(v1.x); a1 += bfhi(v1.x); a2 += bflo(v1.y); a3 += bfhi(v1.y);
        a0 += bflo(v2.x); a1 += bfhi(v2.x); a2 += bflo(v2.y); a3 += bfhi(v2.y);
        a0 += bflo(v3.x); a1 += bfhi(v3.x); a2 += bflo(v3.y); a3 += bfhi(v3.y);
    }
    for (; k < n; ++k) {
        uint2 v0 = tg2[(size_t)eidx[s + k] * 10 + t];
        a0 += bflo(v0.x); a1 += bfhi(v0.x); a2 += bflo(v0.y); a3 += bfhi(v0.y);
    }
    float d = dinv[node];
    float4 bb = *(const float4*)(b2 + 4 * t);
    float4 o;
    o.x = a0 * d + bb.x;
    o.y = a1 * d + bb.y;
    o.z = a2 * d + bb.z;
    o.w = a3 * d + bb.w;
    *(float4*)(out + (size_t)node * F3 + 4 * t) = o;
}

extern "C" void kernel_launch(void* const* d_in, const int* in_sizes, int n_in,
                              void* d_out, int out_size, void* d_ws, size_t ws_size,
                              hipStream_t stream) {
    const float* x  = (const float*)d_in[0];
    const int*   ei = (const int*)d_in[1];
    const float* W1 = (const float*)d_in[2];
    const float* b1 = (const float*)d_in[3];
    const float* W2 = (const float*)d_in[4];
    const float* b2 = (const float*)d_in[5];
    float* out = (float*)d_out;

    const int* row = ei;
    const int* col = ei + EE;

    // ws: cnt[N] | cursor[N] | dinv[N] | bcur[NBUK] | pad | eidx[NBUK*DCAP]
    //     | xh[N*64 u32] | agg[N*64 u32] | W1p | W2p        ~59 MB
    // overlays: rec (NBUK*DCAP u32 = 6.4MB) on agg (dead until k_agg1);
    // tg (N*40 bf16 packed, 8MB) on xh (dead after k_agg1; agg1/gemm separate
    // launches — round-4 lesson).
    // ints before eidx: 3*100000 + 391 + 9 = 300400 -> eidx 16B-aligned;
    // ints before xh: 300400 + 1601536 = 1901936 -> xh byte 7607744 %16==0.
    int* cnt     = (int*)d_ws;
    int* cursor  = cnt + NN;
    float* dinv  = (float*)(cursor + NN);
    int* bcur    = (int*)(dinv + NN);
    int* eidx    = bcur + NBUK + 9;            // pad -> 16B alignment
    unsigned* xh  = (unsigned*)(eidx + NBUK * DCAP);
    unsigned* agg = xh + (size_t)NN * 64;
    unsigned* rec = agg;                               // overlay on agg (6.4MB)
    unsigned short* tg = (unsigned short*)xh;          // overlay on xh (8MB)
    __hip_bfloat16* W1p = (__hip_bfloat16*)(agg + (size_t)NN * 64);
    __hip_bfloat16* W2p = W1p + (size_t)F1 * F2;

    hipMemsetAsync(bcur, 0, NBUK * sizeof(int), stream);
    k_scatprep<<<NBLK + XB2 + WB, 256, 0, stream>>>(
        row, col, bcur, rec, (const float4*)x, (uint2*)xh, W1, W2, W1p, W2p);
    k_csr<<<NBUK, 256, 0, stream>>>(bcur, rec, eidx, cnt, cursor, dinv);

    k_agg1<<<(NN + 3) / 4, 256, 0, stream>>>(cursor, cnt, eidx, dinv, xh, agg);
    k_gemm_mfma<<<(NN + MROWS - 1) / MROWS, 256, 0, stream>>>(
        (const __hip_bfloat16*)agg, W1p, b1, W2p, dinv, tg);
    k_agg2<<<(NN + 23) / 24, 256, 0, stream>>>(cursor, cnt, eidx, dinv, tg, b2, out);
}